// Round 10
// baseline (1609.515 us; speedup 1.0000x reference)
//
#include <hip/hip_runtime.h>

typedef __attribute__((ext_vector_type(8))) short short8;
typedef __attribute__((ext_vector_type(4))) float f32x4;

#define MFMA16(a, b, c) __builtin_amdgcn_mfma_f32_16x16x32_bf16((a), (b), (c), 0, 0, 0)

constexpr int Bv  = 32;    // batch
constexpr int Lv  = 168;   // encoder length
constexpr int Sv  = 512;   // sites
constexpr int HZv = 24;    // horizon
constexpr int Mv  = 64;    // sequences per block (256 blocks, 1 per CU)
constexpr int HSTR = 88;   // h-row stride (shorts)
constexpr int HBUF = Mv * HSTR;   // 5632 shorts; slots: 0,1 = h0 dbuf; 2,3 = h1 dbuf

// gate prescale factors folded into weights/biases at pack time:
// i,f,o rows: -log2(e)  -> sigm(x) = rcp(1 + exp2(p)),  p = -log2e*x
// g row:     2*log2(e)  -> tanh(x) = (exp2(p)-1)/(exp2(p)+1), p = 2log2e*x
__device__ __constant__ float GF[4] = {-1.44269504088896f, -1.44269504088896f,
                                        2.88539008177793f, -1.44269504088896f};

__device__ __forceinline__ float b2f(short s) {
    unsigned u = ((unsigned)(unsigned short)s) << 16;
    return __builtin_bit_cast(float, u);
}
__device__ __forceinline__ short f2b(float f) {
    unsigned u = __builtin_bit_cast(unsigned, f);
    unsigned r = (u + 0x7FFFu + ((u >> 16) & 1u)) >> 16;   // RNE
    return (short)(unsigned short)r;
}
__device__ __forceinline__ unsigned pkbf16(float lo, float hi) {
    unsigned r;
    asm("v_cvt_pk_bf16_f32 %0, %1, %2" : "=v"(r) : "v"(lo), "v"(hi));
    return r;
}

// LSTM cell epilogue, shared-rcp form, scalar (r22-proven).
//   sig(i)*tanh(g) = (e_g-1)*rcp(d_i*d_g);  sig(o)*tanh(c) = (e_c-1)*rcp(d_o*d_c)
// 5 exp2 + 3 rcp per element. pc clamped at 88 keeps all products finite.
__device__ __forceinline__ float cell1(float pi, float pf, float pg, float po,
                                       float& c) {
    const float ei = __builtin_amdgcn_exp2f(pi);
    const float ef = __builtin_amdgcn_exp2f(pf);
    const float eg = __builtin_amdgcn_exp2f(pg);
    const float eo = __builtin_amdgcn_exp2f(po);
    const float rig = __builtin_amdgcn_rcpf((1.0f + ei) * (1.0f + eg));
    const float rf  = __builtin_amdgcn_rcpf(1.0f + ef);
    c = rf * c + (eg - 1.0f) * rig;
    const float pc = fminf(c * 2.88539008177793f, 88.0f);
    const float ec = __builtin_amdgcn_exp2f(pc);
    const float roc = __builtin_amdgcn_rcpf((1.0f + eo) * (1.0f + ec));
    return (ec - 1.0f) * roc;
}

__device__ __forceinline__ void hi8s(const float* __restrict__ p, float s, short8& hi) {
#pragma unroll
    for (int j = 0; j < 8; ++j) hi[j] = f2b(p[j] * s);
}

// r23: r22 pipeline (L0 waves 0-7 @ step t+1, L1 waves 8-15 @ step t, one
// barrier/interval) + Whh1 promoted to L1-wave REGISTERS (wreg2, 32 VGPR).
// Wlds deleted entirely -> L1's 16-MFMA cluster is pure-register-B, no lgkm
// waits; LDS 78->46 KB. Register law: L1 peak = 64 weight + ~55 working
// ~= 119 < 128 cap, and NO streaming window coexists (r19's fatal combo).
__global__ __launch_bounds__(1024)
void sitewise_lstm(const float* __restrict__ x_seq,
                   const float* __restrict__ Wih0, const float* __restrict__ Whh0,
                   const float* __restrict__ bih0, const float* __restrict__ bhh0,
                   const float* __restrict__ Wih1, const float* __restrict__ Whh1,
                   const float* __restrict__ bih1, const float* __restrict__ bhh1,
                   const float* __restrict__ Wcih, const float* __restrict__ Wchh,
                   const float* __restrict__ bcih, const float* __restrict__ bchh,
                   const float* __restrict__ Wout, const float* __restrict__ bout,
                   float* __restrict__ out)
{
    __shared__ __align__(16) short Hhi[4 * HBUF];    // 45 KB: h0 dbuf, h1 dbuf
    __shared__ __align__(16) float woutF[64];
    __shared__ __align__(16) float ybufF[Mv];

    const int tid  = threadIdx.x;
    const int wv   = tid >> 6;        // 0..15
    const int lane = tid & 63;
    const int q    = lane >> 4;
    const int col  = lane & 15;
    const bool isL0 = (wv < 8);
    const int wq   = wv & 7;
    const int mh   = wq >> 2;         // 0..1: m in [32mh, 32mh+32)
    const int U    = wq & 3;          // u in [16U, 16U+16)
    const int bid  = blockIdx.x;
    const int b    = bid >> 3;
    const int s0   = (bid & 7) << 6;
    const int uu   = U * 16 + col;
    const int me   = mh * 32 + q * 4;                  // epilogue m base (+ mt*16 + r)

    const int roA  = (mh * 32 + col) * HSTR + q * 8;   // A-frag read (+ mt*16*HSTR, +32 for kc1)
    const int wiA  = me * HSTR + uu;                   // h write (+ (mt*16+r)*HSTR)

    // ---- zero H buffers; wout ----
    for (int i = tid; i < 4 * HBUF / 2; i += 1024) ((int*)Hhi)[i] = 0;
    if (tid < 64) woutF[tid] = Wout[tid];

    const float* xbF = x_seq + b * Lv * Sv + s0;

    // ---- per-wave-role scalars + TWO register weight matrices ----
    // L0: wreg = Whh0, wreg2 = (dup Whh0, unused); L1: wreg = Wih1, wreg2 = Whh1
    float ba[4], we[4];
    short8 wreg[8], wreg2[8];
    const float* WmA = isL0 ? Whh0 : Wih1;
    const float* WmB = isL0 ? Whh0 : Whh1;
#pragma unroll
    for (int g = 0; g < 4; ++g) {
        const int j = g * 64 + uu;
        ba[g] = (isL0 ? (bih0[j] + bhh0[j]) : (bih1[j] + bhh1[j])) * GF[g];
        we[g] = Wih0[j] * GF[g];       // used by L0 only in encoder
#pragma unroll
        for (int kc = 0; kc < 2; ++kc) {
            hi8s(WmA + j * 64 + kc * 32 + q * 8, GF[g], wreg[kc * 4 + g]);
            hi8s(WmB + j * 64 + kc * 32 + q * 8, GF[g], wreg2[kc * 4 + g]);
        }
    }

    float cs[8];         // c-state: L0 waves hold c0, L1 waves hold c1
#pragma unroll
    for (int i = 0; i < 8; ++i) cs[i] = 0.f;

    __syncthreads();   // Hhi zeroed visible

// layer-0 step T: read h0 slot RP (0/1), write h0 slot WP
#define L0BODY(T, RP, WP) do {                                                        \
        _Pragma("unroll")                                                             \
        for (int mt = 0; mt < 2; ++mt) {                                              \
            const f32x4 xv = *(const f32x4*)(xbF + (T) * Sv + me + mt * 16);          \
            const short8 a0 = *(const short8*)(Hhi + (RP) * HBUF + roA + mt * 16 * HSTR);      \
            const short8 a1 = *(const short8*)(Hhi + (RP) * HBUF + roA + mt * 16 * HSTR + 32); \
            f32x4 pre[4];                                                             \
            _Pragma("unroll")                                                         \
            for (int g = 0; g < 4; ++g) pre[g] = (f32x4){ba[g], ba[g], ba[g], ba[g]}; \
            _Pragma("unroll")                                                         \
            for (int g = 0; g < 4; ++g) pre[g] = MFMA16(a0, wreg[g],     pre[g]);     \
            _Pragma("unroll")                                                         \
            for (int g = 0; g < 4; ++g) pre[g] = MFMA16(a1, wreg[4 + g], pre[g]);     \
            float hv[4];                                                              \
            _Pragma("unroll")                                                         \
            for (int r = 0; r < 4; ++r) {                                             \
                const float xw = xv[r];                                               \
                hv[r] = cell1(pre[0][r] + xw * we[0], pre[1][r] + xw * we[1],         \
                              pre[2][r] + xw * we[2], pre[3][r] + xw * we[3],         \
                              cs[mt * 4 + r]);                                        \
            }                                                                         \
            const unsigned p01 = pkbf16(hv[0], hv[1]);                                \
            const unsigned p23 = pkbf16(hv[2], hv[3]);                                \
            Hhi[(WP) * HBUF + wiA + (mt * 16 + 0) * HSTR] = (short)p01;               \
            Hhi[(WP) * HBUF + wiA + (mt * 16 + 1) * HSTR] = (short)(p01 >> 16);       \
            Hhi[(WP) * HBUF + wiA + (mt * 16 + 2) * HSTR] = (short)p23;               \
            Hhi[(WP) * HBUF + wiA + (mt * 16 + 3) * HSTR] = (short)(p23 >> 16);       \
        }                                                                             \
    } while (0)

// layer-1 step: read h0 slot RP0 (0/1), h1 slot RPH (2/3), write h1 slot WPH
// all-register B operands: wreg = Wih1, wreg2 = Whh1
#define L1BODY(RP0, RPH, WPH) do {                                                    \
        _Pragma("unroll")                                                             \
        for (int mt = 0; mt < 2; ++mt) {                                              \
            const short8 b0 = *(const short8*)(Hhi + (RP0) * HBUF + roA + mt * 16 * HSTR);      \
            const short8 b1 = *(const short8*)(Hhi + (RP0) * HBUF + roA + mt * 16 * HSTR + 32); \
            const short8 d0 = *(const short8*)(Hhi + (RPH) * HBUF + roA + mt * 16 * HSTR);      \
            const short8 d1 = *(const short8*)(Hhi + (RPH) * HBUF + roA + mt * 16 * HSTR + 32); \
            f32x4 pre[4];                                                             \
            _Pragma("unroll")                                                         \
            for (int g = 0; g < 4; ++g) pre[g] = (f32x4){ba[g], ba[g], ba[g], ba[g]}; \
            _Pragma("unroll")                                                         \
            for (int g = 0; g < 4; ++g) pre[g] = MFMA16(b0, wreg[g],      pre[g]);    \
            _Pragma("unroll")                                                         \
            for (int g = 0; g < 4; ++g) pre[g] = MFMA16(b1, wreg[4 + g],  pre[g]);    \
            _Pragma("unroll")                                                         \
            for (int g = 0; g < 4; ++g) pre[g] = MFMA16(d0, wreg2[g],     pre[g]);    \
            _Pragma("unroll")                                                         \
            for (int g = 0; g < 4; ++g) pre[g] = MFMA16(d1, wreg2[4 + g], pre[g]);    \
            float hv[4];                                                              \
            _Pragma("unroll")                                                         \
            for (int r = 0; r < 4; ++r)                                               \
                hv[r] = cell1(pre[0][r], pre[1][r], pre[2][r], pre[3][r],             \
                              cs[mt * 4 + r]);                                        \
            const unsigned p01 = pkbf16(hv[0], hv[1]);                                \
            const unsigned p23 = pkbf16(hv[2], hv[3]);                                \
            Hhi[(WPH) * HBUF + wiA + (mt * 16 + 0) * HSTR] = (short)p01;              \
            Hhi[(WPH) * HBUF + wiA + (mt * 16 + 1) * HSTR] = (short)(p01 >> 16);      \
            Hhi[(WPH) * HBUF + wiA + (mt * 16 + 2) * HSTR] = (short)p23;              \
            Hhi[(WPH) * HBUF + wiA + (mt * 16 + 3) * HSTR] = (short)(p23 >> 16);      \
        }                                                                             \
    } while (0)

    // ---- encoder: 169 barrier intervals; interval k runs L0(k) || L1(k-1) ----
    // h0(t) -> slot t&1; h1(t) -> slot 2+(t&1). Slots 1,3 start zeroed (= t=-1).
    if (isL0) L0BODY(0, 1, 0);
    __syncthreads();
    for (int k = 1; k < 167; k += 2) {
        // odd interval k: L0(k): rd h0[0] wr h0[1]; L1(k-1): rd h0[0],h1[3] wr h1[2]
        if (isL0) L0BODY(k, 0, 1); else L1BODY(0, 3, 2);
        __syncthreads();
        // even interval k+1: L0: rd h0[1] wr h0[0]; L1(k): rd h0[1],h1[2] wr h1[3]
        if (isL0) L0BODY(k + 1, 1, 0); else L1BODY(1, 2, 3);
        __syncthreads();
    }
    if (isL0) L0BODY(167, 0, 1); else L1BODY(0, 3, 2);   // interval 167 (odd)
    __syncthreads();
    if (!isL0) L1BODY(1, 2, 3);                          // interval 168: L1(167) only
    __syncthreads();
    // h1(167) now in slot 3; c1 state lives in L1 waves' cs[8]

    // ================= decoder (runs on L1 waves; projection on all) =================
#pragma unroll
    for (int g = 0; g < 4; ++g) {
        const int j = g * 64 + uu;
        ba[g] = (bcih[j] + bchh[j]) * GF[g];
        we[g] = Wcih[j] * GF[g];
#pragma unroll
        for (int kc = 0; kc < 2; ++kc)
            hi8s(Wchh + j * 64 + kc * 32 + q * 8, GF[g], wreg[kc * 4 + g]);
    }
    if (tid < Mv) ybufF[tid] = xbF[(Lv - 1) * Sv + tid];
    __syncthreads();   // ybufF visible (h1 slot 3 already visible)

    const float boutF = bout[0];
    float* outp = out + b * HZv * Sv + s0;

#define DECBODY(T, RPH, WPH) do {                                                     \
        if (!isL0) {                                                                  \
            _Pragma("unroll")                                                         \
            for (int mt = 0; mt < 2; ++mt) {                                          \
                const f32x4 yv = *(const f32x4*)(ybufF + me + mt * 16);               \
                const short8 a0 = *(const short8*)(Hhi + (RPH) * HBUF + roA + mt * 16 * HSTR);      \
                const short8 a1 = *(const short8*)(Hhi + (RPH) * HBUF + roA + mt * 16 * HSTR + 32); \
                f32x4 pre[4];                                                         \
                _Pragma("unroll")                                                     \
                for (int g = 0; g < 4; ++g) pre[g] = (f32x4){ba[g], ba[g], ba[g], ba[g]}; \
                _Pragma("unroll")                                                     \
                for (int g = 0; g < 4; ++g) pre[g] = MFMA16(a0, wreg[g],     pre[g]); \
                _Pragma("unroll")                                                     \
                for (int g = 0; g < 4; ++g) pre[g] = MFMA16(a1, wreg[4 + g], pre[g]); \
                float hv[4];                                                          \
                _Pragma("unroll")                                                     \
                for (int r = 0; r < 4; ++r) {                                         \
                    const float xw = yv[r];                                           \
                    hv[r] = cell1(pre[0][r] + xw * we[0], pre[1][r] + xw * we[1],     \
                                  pre[2][r] + xw * we[2], pre[3][r] + xw * we[3],     \
                                  cs[mt * 4 + r]);                                    \
                }                                                                     \
                const unsigned p01 = pkbf16(hv[0], hv[1]);                            \
                const unsigned p23 = pkbf16(hv[2], hv[3]);                            \
                Hhi[(WPH) * HBUF + wiA + (mt * 16 + 0) * HSTR] = (short)p01;          \
                Hhi[(WPH) * HBUF + wiA + (mt * 16 + 1) * HSTR] = (short)(p01 >> 16);  \
                Hhi[(WPH) * HBUF + wiA + (mt * 16 + 2) * HSTR] = (short)p23;          \
                Hhi[(WPH) * HBUF + wiA + (mt * 16 + 3) * HSTR] = (short)(p23 >> 16);  \
            }                                                                         \
        }                                                                             \
        __syncthreads();   /* h(new) visible for y projection */                      \
        {                  /* all 1024 threads: 16 lanes per m, 4 k each */           \
            const int m  = tid >> 4;                                                  \
            const int pp = tid & 15;                                                  \
            float s = 0.f;                                                            \
            _Pragma("unroll")                                                         \
            for (int k2 = 0; k2 < 4; ++k2)                                            \
                s += b2f(Hhi[(WPH) * HBUF + m * HSTR + pp * 4 + k2]) * woutF[pp * 4 + k2]; \
            s += __shfl_xor(s, 1, 64);                                                \
            s += __shfl_xor(s, 2, 64);                                                \
            s += __shfl_xor(s, 4, 64);                                                \
            s += __shfl_xor(s, 8, 64);                                                \
            if (pp == 0) {                                                            \
                const float y = s + boutF;                                            \
                outp[(T) * Sv + m] = y;                                               \
                ybufF[m] = y;                                                         \
            }                                                                         \
        }                                                                             \
        __syncthreads();   /* ybufF visible for next step */                          \
    } while (0)

    for (int t = 0; t < HZv; t += 2) {
        DECBODY(t,     3, 2);
        DECBODY(t + 1, 2, 3);
    }
#undef DECBODY
#undef L1BODY
#undef L0BODY
}

extern "C" void kernel_launch(void* const* d_in, const int* in_sizes, int n_in,
                              void* d_out, int out_size, void* d_ws, size_t ws_size,
                              hipStream_t stream)
{
    const float* x_seq = (const float*)d_in[0];
    const float* Wih0  = (const float*)d_in[1];
    const float* Whh0  = (const float*)d_in[2];
    const float* bih0  = (const float*)d_in[3];
    const float* bhh0  = (const float*)d_in[4];
    const float* Wih1  = (const float*)d_in[5];
    const float* Whh1  = (const float*)d_in[6];
    const float* bih1  = (const float*)d_in[7];
    const float* bhh1  = (const float*)d_in[8];
    const float* Wcih  = (const float*)d_in[9];
    const float* Wchh  = (const float*)d_in[10];
    const float* bcih  = (const float*)d_in[11];
    const float* bchh  = (const float*)d_in[12];
    const float* Wout  = (const float*)d_in[13];
    const float* bout  = (const float*)d_in[14];
    float* out = (float*)d_out;

    hipLaunchKernelGGL(sitewise_lstm, dim3(Bv * (Sv / Mv)), dim3(1024), 0, stream,
                       x_seq, Wih0, Whh0, bih0, bhh0, Wih1, Whh1, bih1, bhh1,
                       Wcih, Wchh, bcih, bchh, Wout, bout, out);
}

// Round 11
// 468.865 us; speedup vs baseline: 3.4328x; 3.4328x over previous
//
#include <hip/hip_runtime.h>

typedef __attribute__((ext_vector_type(8))) short short8;
typedef __attribute__((ext_vector_type(4))) float f32x4;

#define MFMA16(a, b, c) __builtin_amdgcn_mfma_f32_16x16x32_bf16((a), (b), (c), 0, 0, 0)

constexpr int Bv  = 32;    // batch
constexpr int Lv  = 168;   // encoder length
constexpr int Sv  = 512;   // sites
constexpr int HZv = 24;    // horizon
constexpr int Mv  = 64;    // sequences per block (256 blocks, 1 per CU)
constexpr int HSTR = 88;   // h-row stride (shorts)
constexpr int HBUF = Mv * HSTR;   // 5632 shorts; slots: 0,1 = h0 dbuf; 2,3 = h1 dbuf
constexpr int WFR  = 512;         // shorts per MFMA B-fragment (64 lanes x 8)

// gate prescale factors folded into weights/biases at pack time:
// i,f,o rows: -log2(e)  -> sigm(x) = rcp(1 + exp2(p)),  p = -log2e*x
// g row:     2*log2(e)  -> tanh(x) = (exp2(p)-1)/(exp2(p)+1), p = 2log2e*x
__device__ __constant__ float GF[4] = {-1.44269504088896f, -1.44269504088896f,
                                        2.88539008177793f, -1.44269504088896f};

__device__ __forceinline__ float b2f(short s) {
    unsigned u = ((unsigned)(unsigned short)s) << 16;
    return __builtin_bit_cast(float, u);
}
__device__ __forceinline__ short f2b(float f) {
    unsigned u = __builtin_bit_cast(unsigned, f);
    unsigned r = (u + 0x7FFFu + ((u >> 16) & 1u)) >> 16;   // RNE
    return (short)(unsigned short)r;
}
__device__ __forceinline__ unsigned pkbf16(float lo, float hi) {
    unsigned r;
    asm("v_cvt_pk_bf16_f32 %0, %1, %2" : "=v"(r) : "v"(lo), "v"(hi));
    return r;
}

// LSTM cell epilogue, shared-rcp form, scalar (r22-proven).
//   sig(i)*tanh(g) = (e_g-1)*rcp(d_i*d_g);  sig(o)*tanh(c) = (e_c-1)*rcp(d_o*d_c)
// 5 exp2 + 3 rcp per element. pc clamped at 88 keeps all products finite.
__device__ __forceinline__ float cell1(float pi, float pf, float pg, float po,
                                       float& c) {
    const float ei = __builtin_amdgcn_exp2f(pi);
    const float ef = __builtin_amdgcn_exp2f(pf);
    const float eg = __builtin_amdgcn_exp2f(pg);
    const float eo = __builtin_amdgcn_exp2f(po);
    const float rig = __builtin_amdgcn_rcpf((1.0f + ei) * (1.0f + eg));
    const float rf  = __builtin_amdgcn_rcpf(1.0f + ef);
    c = rf * c + (eg - 1.0f) * rig;
    const float pc = fminf(c * 2.88539008177793f, 88.0f);
    const float ec = __builtin_amdgcn_exp2f(pc);
    const float roc = __builtin_amdgcn_rcpf((1.0f + eo) * (1.0f + ec));
    return (ec - 1.0f) * roc;
}

__device__ __forceinline__ void hi8s(const float* __restrict__ p, float s, short8& hi) {
#pragma unroll
    for (int j = 0; j < 8; ++j) hi[j] = f2b(p[j] * s);
}

// r24: r22 (best: 458us; L0/L1 wave-specialized pipeline, Whh1 LDS-streamed,
// shared-rcp scalar epilogue) + the block's ENTIRE x-slab (168x64 f32 = 43KB)
// staged into LDS once at start. Removes the per-interval global x-load
// (L2 ~200cy / HBM ~900cy, consumed same-interval) from the encoder critical
// path. r23's register promotion spilled (3rd time) -> reverted.
__global__ __launch_bounds__(1024)
void sitewise_lstm(const float* __restrict__ x_seq,
                   const float* __restrict__ Wih0, const float* __restrict__ Whh0,
                   const float* __restrict__ bih0, const float* __restrict__ bhh0,
                   const float* __restrict__ Wih1, const float* __restrict__ Whh1,
                   const float* __restrict__ bih1, const float* __restrict__ bhh1,
                   const float* __restrict__ Wcih, const float* __restrict__ Wchh,
                   const float* __restrict__ bcih, const float* __restrict__ bchh,
                   const float* __restrict__ Wout, const float* __restrict__ bout,
                   float* __restrict__ out)
{
    __shared__ __align__(16) short Wlds[32 * WFR];   // 32 KB: Whh1 frags
    __shared__ __align__(16) short Hhi[4 * HBUF];    // 45 KB: h0 dbuf, h1 dbuf
    __shared__ __align__(16) float Xlds[Lv * Mv];    // 43 KB: x slab [t][m]
    __shared__ __align__(16) float woutF[64];
    __shared__ __align__(16) float ybufF[Mv];

    const int tid  = threadIdx.x;
    const int wv   = tid >> 6;        // 0..15
    const int lane = tid & 63;
    const int q    = lane >> 4;
    const int col  = lane & 15;
    const bool isL0 = (wv < 8);
    const int wq   = wv & 7;
    const int mh   = wq >> 2;         // 0..1: m in [32mh, 32mh+32)
    const int U    = wq & 3;          // u in [16U, 16U+16)
    const int bid  = blockIdx.x;
    const int b    = bid >> 3;
    const int s0   = (bid & 7) << 6;
    const int uu   = U * 16 + col;
    const int me   = mh * 32 + q * 4;                  // epilogue m base (+ mt*16 + r)

    const int roA  = (mh * 32 + col) * HSTR + q * 8;   // A-frag read (+ mt*16*HSTR, +32 for kc1)
    const int wiA  = me * HSTR + uu;                   // h write (+ (mt*16+r)*HSTR)
    const int wb   = (U * 8) * WFR + lane * 8;         // Wlds frag base (+ (kc*4+g)*WFR)

    // ---- zero H buffers; wout ----
    for (int i = tid; i < 4 * HBUF / 2; i += 1024) ((int*)Hhi)[i] = 0;
    if (tid < 64) woutF[tid] = Wout[tid];

    const float* xbF = x_seq + b * Lv * Sv + s0;

    // ---- stage x slab into LDS (coalesced 256B rows), once ----
    for (int idx = tid; idx < Lv * Mv; idx += 1024)
        Xlds[idx] = xbF[(idx >> 6) * Sv + (idx & 63)];

    // ---- pack PRESCALED Whh1 into LDS fragments ----
    for (int idx = tid; idx < 32 * 64; idx += 1024) {
        const int fid = idx >> 6;      // Uw*8 + kc*4 + g
        const int ln  = idx & 63;
        const int Uw  = fid >> 3;
        const int kc  = (fid >> 2) & 1;
        const int g   = fid & 3;
        const int j   = g * 64 + Uw * 16 + (ln & 15);
        const int cc  = kc * 32 + (ln >> 4) * 8;
        short8 hv; hi8s(Whh1 + j * 64 + cc, GF[g], hv);
        *(short8*)(Wlds + fid * WFR + ln * 8) = hv;
    }

    // ---- per-wave-role scalars + register weight matrix ----
    float ba[4], we[4];
    short8 wreg[8];      // L0: Whh0 frags; L1: Wih1 frags; decoder: Wchh frags
    const float* WmA = isL0 ? Whh0 : Wih1;
#pragma unroll
    for (int g = 0; g < 4; ++g) {
        const int j = g * 64 + uu;
        ba[g] = (isL0 ? (bih0[j] + bhh0[j]) : (bih1[j] + bhh1[j])) * GF[g];
        we[g] = Wih0[j] * GF[g];       // used by L0 only in encoder
#pragma unroll
        for (int kc = 0; kc < 2; ++kc)
            hi8s(WmA + j * 64 + kc * 32 + q * 8, GF[g], wreg[kc * 4 + g]);
    }

    float cs[8];         // c-state: L0 waves hold c0, L1 waves hold c1
#pragma unroll
    for (int i = 0; i < 8; ++i) cs[i] = 0.f;

    __syncthreads();   // Hhi zeroed + Xlds + Wlds packed visible

// layer-0 step T: read h0 slot RP (0/1), write h0 slot WP; x from LDS slab
#define L0BODY(T, RP, WP) do {                                                        \
        _Pragma("unroll")                                                             \
        for (int mt = 0; mt < 2; ++mt) {                                              \
            const f32x4 xv = *(const f32x4*)(Xlds + (T) * Mv + me + mt * 16);         \
            const short8 a0 = *(const short8*)(Hhi + (RP) * HBUF + roA + mt * 16 * HSTR);      \
            const short8 a1 = *(const short8*)(Hhi + (RP) * HBUF + roA + mt * 16 * HSTR + 32); \
            f32x4 pre[4];                                                             \
            _Pragma("unroll")                                                         \
            for (int g = 0; g < 4; ++g) pre[g] = (f32x4){ba[g], ba[g], ba[g], ba[g]}; \
            _Pragma("unroll")                                                         \
            for (int g = 0; g < 4; ++g) pre[g] = MFMA16(a0, wreg[g],     pre[g]);     \
            _Pragma("unroll")                                                         \
            for (int g = 0; g < 4; ++g) pre[g] = MFMA16(a1, wreg[4 + g], pre[g]);     \
            float hv[4];                                                              \
            _Pragma("unroll")                                                         \
            for (int r = 0; r < 4; ++r) {                                             \
                const float xw = xv[r];                                               \
                hv[r] = cell1(pre[0][r] + xw * we[0], pre[1][r] + xw * we[1],         \
                              pre[2][r] + xw * we[2], pre[3][r] + xw * we[3],         \
                              cs[mt * 4 + r]);                                        \
            }                                                                         \
            const unsigned p01 = pkbf16(hv[0], hv[1]);                                \
            const unsigned p23 = pkbf16(hv[2], hv[3]);                                \
            Hhi[(WP) * HBUF + wiA + (mt * 16 + 0) * HSTR] = (short)p01;               \
            Hhi[(WP) * HBUF + wiA + (mt * 16 + 1) * HSTR] = (short)(p01 >> 16);       \
            Hhi[(WP) * HBUF + wiA + (mt * 16 + 2) * HSTR] = (short)p23;               \
            Hhi[(WP) * HBUF + wiA + (mt * 16 + 3) * HSTR] = (short)(p23 >> 16);       \
        }                                                                             \
    } while (0)

// layer-1 step: read h0 slot RP0 (0/1), h1 slot RPH (2/3), write h1 slot WPH
#define L1BODY(RP0, RPH, WPH) do {                                                    \
        _Pragma("unroll")                                                             \
        for (int mt = 0; mt < 2; ++mt) {                                              \
            const short8 b0 = *(const short8*)(Hhi + (RP0) * HBUF + roA + mt * 16 * HSTR);      \
            const short8 b1 = *(const short8*)(Hhi + (RP0) * HBUF + roA + mt * 16 * HSTR + 32); \
            const short8 d0 = *(const short8*)(Hhi + (RPH) * HBUF + roA + mt * 16 * HSTR);      \
            const short8 d1 = *(const short8*)(Hhi + (RPH) * HBUF + roA + mt * 16 * HSTR + 32); \
            f32x4 pre[4];                                                             \
            _Pragma("unroll")                                                         \
            for (int g = 0; g < 4; ++g) pre[g] = (f32x4){ba[g], ba[g], ba[g], ba[g]}; \
            _Pragma("unroll")                                                         \
            for (int g = 0; g < 4; ++g) pre[g] = MFMA16(b0, wreg[g],     pre[g]);     \
            _Pragma("unroll")                                                         \
            for (int g = 0; g < 4; ++g) pre[g] = MFMA16(b1, wreg[4 + g], pre[g]);     \
            _Pragma("unroll")                                                         \
            for (int g = 0; g < 4; ++g) {                                             \
                const short8 wf = *(const short8*)(Wlds + wb + g * WFR);              \
                pre[g] = MFMA16(d0, wf, pre[g]);                                      \
            }                                                                         \
            _Pragma("unroll")                                                         \
            for (int g = 0; g < 4; ++g) {                                             \
                const short8 wf = *(const short8*)(Wlds + wb + (4 + g) * WFR);        \
                pre[g] = MFMA16(d1, wf, pre[g]);                                      \
            }                                                                         \
            float hv[4];                                                              \
            _Pragma("unroll")                                                         \
            for (int r = 0; r < 4; ++r)                                               \
                hv[r] = cell1(pre[0][r], pre[1][r], pre[2][r], pre[3][r],             \
                              cs[mt * 4 + r]);                                        \
            const unsigned p01 = pkbf16(hv[0], hv[1]);                                \
            const unsigned p23 = pkbf16(hv[2], hv[3]);                                \
            Hhi[(WPH) * HBUF + wiA + (mt * 16 + 0) * HSTR] = (short)p01;              \
            Hhi[(WPH) * HBUF + wiA + (mt * 16 + 1) * HSTR] = (short)(p01 >> 16);      \
            Hhi[(WPH) * HBUF + wiA + (mt * 16 + 2) * HSTR] = (short)p23;              \
            Hhi[(WPH) * HBUF + wiA + (mt * 16 + 3) * HSTR] = (short)(p23 >> 16);      \
        }                                                                             \
    } while (0)

    // ---- encoder: 169 barrier intervals; interval k runs L0(k) || L1(k-1) ----
    // h0(t) -> slot t&1; h1(t) -> slot 2+(t&1). Slots 1,3 start zeroed (= t=-1).
    if (isL0) L0BODY(0, 1, 0);
    __syncthreads();
    for (int k = 1; k < 167; k += 2) {
        // odd interval k: L0(k): rd h0[0] wr h0[1]; L1(k-1): rd h0[0],h1[3] wr h1[2]
        if (isL0) L0BODY(k, 0, 1); else L1BODY(0, 3, 2);
        __syncthreads();
        // even interval k+1: L0: rd h0[1] wr h0[0]; L1(k): rd h0[1],h1[2] wr h1[3]
        if (isL0) L0BODY(k + 1, 1, 0); else L1BODY(1, 2, 3);
        __syncthreads();
    }
    if (isL0) L0BODY(167, 0, 1); else L1BODY(0, 3, 2);   // interval 167 (odd)
    __syncthreads();
    if (!isL0) L1BODY(1, 2, 3);                          // interval 168: L1(167) only
    __syncthreads();
    // h1(167) now in slot 3; c1 state lives in L1 waves' cs[8]

    // ================= decoder (runs on L1 waves; projection on all) =================
#pragma unroll
    for (int g = 0; g < 4; ++g) {
        const int j = g * 64 + uu;
        ba[g] = (bcih[j] + bchh[j]) * GF[g];
        we[g] = Wcih[j] * GF[g];
#pragma unroll
        for (int kc = 0; kc < 2; ++kc)
            hi8s(Wchh + j * 64 + kc * 32 + q * 8, GF[g], wreg[kc * 4 + g]);
    }
    if (tid < Mv) ybufF[tid] = Xlds[(Lv - 1) * Mv + tid];
    __syncthreads();   // ybufF visible (h1 slot 3 already visible)

    const float boutF = bout[0];
    float* outp = out + b * HZv * Sv + s0;

#define DECBODY(T, RPH, WPH) do {                                                     \
        if (!isL0) {                                                                  \
            _Pragma("unroll")                                                         \
            for (int mt = 0; mt < 2; ++mt) {                                          \
                const f32x4 yv = *(const f32x4*)(ybufF + me + mt * 16);               \
                const short8 a0 = *(const short8*)(Hhi + (RPH) * HBUF + roA + mt * 16 * HSTR);      \
                const short8 a1 = *(const short8*)(Hhi + (RPH) * HBUF + roA + mt * 16 * HSTR + 32); \
                f32x4 pre[4];                                                         \
                _Pragma("unroll")                                                     \
                for (int g = 0; g < 4; ++g) pre[g] = (f32x4){ba[g], ba[g], ba[g], ba[g]}; \
                _Pragma("unroll")                                                     \
                for (int g = 0; g < 4; ++g) pre[g] = MFMA16(a0, wreg[g],     pre[g]); \
                _Pragma("unroll")                                                     \
                for (int g = 0; g < 4; ++g) pre[g] = MFMA16(a1, wreg[4 + g], pre[g]); \
                float hv[4];                                                          \
                _Pragma("unroll")                                                     \
                for (int r = 0; r < 4; ++r) {                                         \
                    const float xw = yv[r];                                           \
                    hv[r] = cell1(pre[0][r] + xw * we[0], pre[1][r] + xw * we[1],     \
                                  pre[2][r] + xw * we[2], pre[3][r] + xw * we[3],     \
                                  cs[mt * 4 + r]);                                    \
                }                                                                     \
                const unsigned p01 = pkbf16(hv[0], hv[1]);                            \
                const unsigned p23 = pkbf16(hv[2], hv[3]);                            \
                Hhi[(WPH) * HBUF + wiA + (mt * 16 + 0) * HSTR] = (short)p01;          \
                Hhi[(WPH) * HBUF + wiA + (mt * 16 + 1) * HSTR] = (short)(p01 >> 16);  \
                Hhi[(WPH) * HBUF + wiA + (mt * 16 + 2) * HSTR] = (short)p23;          \
                Hhi[(WPH) * HBUF + wiA + (mt * 16 + 3) * HSTR] = (short)(p23 >> 16);  \
            }                                                                         \
        }                                                                             \
        __syncthreads();   /* h(new) visible for y projection */                      \
        {                  /* all 1024 threads: 16 lanes per m, 4 k each */           \
            const int m  = tid >> 4;                                                  \
            const int pp = tid & 15;                                                  \
            float s = 0.f;                                                            \
            _Pragma("unroll")                                                         \
            for (int k2 = 0; k2 < 4; ++k2)                                            \
                s += b2f(Hhi[(WPH) * HBUF + m * HSTR + pp * 4 + k2]) * woutF[pp * 4 + k2]; \
            s += __shfl_xor(s, 1, 64);                                                \
            s += __shfl_xor(s, 2, 64);                                                \
            s += __shfl_xor(s, 4, 64);                                                \
            s += __shfl_xor(s, 8, 64);                                                \
            if (pp == 0) {                                                            \
                const float y = s + boutF;                                            \
                outp[(T) * Sv + m] = y;                                               \
                ybufF[m] = y;                                                         \
            }                                                                         \
        }                                                                             \
        __syncthreads();   /* ybufF visible for next step */                          \
    } while (0)

    for (int t = 0; t < HZv; t += 2) {
        DECBODY(t,     3, 2);
        DECBODY(t + 1, 2, 3);
    }
#undef DECBODY
#undef L1BODY
#undef L0BODY
}

extern "C" void kernel_launch(void* const* d_in, const int* in_sizes, int n_in,
                              void* d_out, int out_size, void* d_ws, size_t ws_size,
                              hipStream_t stream)
{
    const float* x_seq = (const float*)d_in[0];
    const float* Wih0  = (const float*)d_in[1];
    const float* Whh0  = (const float*)d_in[2];
    const float* bih0  = (const float*)d_in[3];
    const float* bhh0  = (const float*)d_in[4];
    const float* Wih1  = (const float*)d_in[5];
    const float* Whh1  = (const float*)d_in[6];
    const float* bih1  = (const float*)d_in[7];
    const float* bhh1  = (const float*)d_in[8];
    const float* Wcih  = (const float*)d_in[9];
    const float* Wchh  = (const float*)d_in[10];
    const float* bcih  = (const float*)d_in[11];
    const float* bchh  = (const float*)d_in[12];
    const float* Wout  = (const float*)d_in[13];
    const float* bout  = (const float*)d_in[14];
    float* out = (float*)d_out;

    hipLaunchKernelGGL(sitewise_lstm, dim3(Bv * (Sv / Mv)), dim3(1024), 0, stream,
                       x_seq, Wih0, Whh0, bih0, bhh0, Wih1, Whh1, bih1, bhh1,
                       Wcih, Wchh, bcih, bchh, Wout, bout, out);
}

// Round 12
// 452.619 us; speedup vs baseline: 3.5560x; 1.0359x over previous
//
#include <hip/hip_runtime.h>

typedef __attribute__((ext_vector_type(8))) short short8;
typedef __attribute__((ext_vector_type(4))) float f32x4;

#define MFMA16(a, b, c) __builtin_amdgcn_mfma_f32_16x16x32_bf16((a), (b), (c), 0, 0, 0)

// encoder barrier: cross-wave deps are LDS-only, so producer-side lgkmcnt(0)
// + s_barrier suffices (HK/m201-verified pattern). Skips __syncthreads'
// vmcnt(0)/expcnt(0) drain -> next-interval global x loads may stay in flight.
#define ENCBAR() asm volatile("s_waitcnt lgkmcnt(0)\n\ts_barrier" ::: "memory")

constexpr int Bv  = 32;    // batch
constexpr int Lv  = 168;   // encoder length
constexpr int Sv  = 512;   // sites
constexpr int HZv = 24;    // horizon
constexpr int Mv  = 64;    // sequences per block (256 blocks, 1 per CU)
constexpr int HSTR = 88;   // h-row stride (shorts)
constexpr int HBUF = Mv * HSTR;   // 5632 shorts; slots: 0,1 = h0 dbuf; 2,3 = h1 dbuf
constexpr int WFR  = 512;         // shorts per MFMA B-fragment (64 lanes x 8)

// gate prescale factors folded into weights/biases at pack time:
// i,f,o rows: -log2(e)  -> sigm(x) = rcp(1 + exp2(p)),  p = -log2e*x
// g row:     2*log2(e)  -> tanh(x) = (exp2(p)-1)/(exp2(p)+1), p = 2log2e*x
__device__ __constant__ float GF[4] = {-1.44269504088896f, -1.44269504088896f,
                                        2.88539008177793f, -1.44269504088896f};

__device__ __forceinline__ float b2f(short s) {
    unsigned u = ((unsigned)(unsigned short)s) << 16;
    return __builtin_bit_cast(float, u);
}
__device__ __forceinline__ short f2b(float f) {
    unsigned u = __builtin_bit_cast(unsigned, f);
    unsigned r = (u + 0x7FFFu + ((u >> 16) & 1u)) >> 16;   // RNE
    return (short)(unsigned short)r;
}
__device__ __forceinline__ unsigned pkbf16(float lo, float hi) {
    unsigned r;
    asm("v_cvt_pk_bf16_f32 %0, %1, %2" : "=v"(r) : "v"(lo), "v"(hi));
    return r;
}

// LSTM cell epilogue, shared-rcp form, scalar (r22-proven).
//   sig(i)*tanh(g) = (e_g-1)*rcp(d_i*d_g);  sig(o)*tanh(c) = (e_c-1)*rcp(d_o*d_c)
// 5 exp2 + 3 rcp per element. pc clamped at 88 keeps all products finite.
__device__ __forceinline__ float cell1(float pi, float pf, float pg, float po,
                                       float& c) {
    const float ei = __builtin_amdgcn_exp2f(pi);
    const float ef = __builtin_amdgcn_exp2f(pf);
    const float eg = __builtin_amdgcn_exp2f(pg);
    const float eo = __builtin_amdgcn_exp2f(po);
    const float rig = __builtin_amdgcn_rcpf((1.0f + ei) * (1.0f + eg));
    const float rf  = __builtin_amdgcn_rcpf(1.0f + ef);
    c = rf * c + (eg - 1.0f) * rig;
    const float pc = fminf(c * 2.88539008177793f, 88.0f);
    const float ec = __builtin_amdgcn_exp2f(pc);
    const float roc = __builtin_amdgcn_rcpf((1.0f + eo) * (1.0f + ec));
    return (ec - 1.0f) * roc;
}

__device__ __forceinline__ void hi8s(const float* __restrict__ p, float s, short8& hi) {
#pragma unroll
    for (int j = 0; j < 8; ++j) hi[j] = f2b(p[j] * s);
}

// r25: exact r22 (champion, 458.5us: L0/L1 wave-specialized pipeline, Whh1
// LDS-streamed, shared-rcp scalar epilogue, global x loads) with ONE change:
// encoder barriers use raw lgkmcnt(0)+s_barrier instead of __syncthreads
// (drops the vmcnt(0) drain; cross-wave deps are LDS-only). r24's x-LDS slab
// was flat-to-negative -> reverted.
__global__ __launch_bounds__(1024)
void sitewise_lstm(const float* __restrict__ x_seq,
                   const float* __restrict__ Wih0, const float* __restrict__ Whh0,
                   const float* __restrict__ bih0, const float* __restrict__ bhh0,
                   const float* __restrict__ Wih1, const float* __restrict__ Whh1,
                   const float* __restrict__ bih1, const float* __restrict__ bhh1,
                   const float* __restrict__ Wcih, const float* __restrict__ Wchh,
                   const float* __restrict__ bcih, const float* __restrict__ bchh,
                   const float* __restrict__ Wout, const float* __restrict__ bout,
                   float* __restrict__ out)
{
    __shared__ __align__(16) short Wlds[32 * WFR];   // 32 KB: Whh1 frags
    __shared__ __align__(16) short Hhi[4 * HBUF];    // 45 KB: h0 dbuf, h1 dbuf
    __shared__ __align__(16) float woutF[64];
    __shared__ __align__(16) float ybufF[Mv];

    const int tid  = threadIdx.x;
    const int wv   = tid >> 6;        // 0..15
    const int lane = tid & 63;
    const int q    = lane >> 4;
    const int col  = lane & 15;
    const bool isL0 = (wv < 8);
    const int wq   = wv & 7;
    const int mh   = wq >> 2;         // 0..1: m in [32mh, 32mh+32)
    const int U    = wq & 3;          // u in [16U, 16U+16)
    const int bid  = blockIdx.x;
    const int b    = bid >> 3;
    const int s0   = (bid & 7) << 6;
    const int uu   = U * 16 + col;
    const int me   = mh * 32 + q * 4;                  // epilogue m base (+ mt*16 + r)

    const int roA  = (mh * 32 + col) * HSTR + q * 8;   // A-frag read (+ mt*16*HSTR, +32 for kc1)
    const int wiA  = me * HSTR + uu;                   // h write (+ (mt*16+r)*HSTR)
    const int wb   = (U * 8) * WFR + lane * 8;         // Wlds frag base (+ (kc*4+g)*WFR)

    // ---- zero H buffers; wout ----
    for (int i = tid; i < 4 * HBUF / 2; i += 1024) ((int*)Hhi)[i] = 0;
    if (tid < 64) woutF[tid] = Wout[tid];

    const float* xbF = x_seq + b * Lv * Sv + s0;

    // ---- pack PRESCALED Whh1 into LDS fragments ----
    for (int idx = tid; idx < 32 * 64; idx += 1024) {
        const int fid = idx >> 6;      // Uw*8 + kc*4 + g
        const int ln  = idx & 63;
        const int Uw  = fid >> 3;
        const int kc  = (fid >> 2) & 1;
        const int g   = fid & 3;
        const int j   = g * 64 + Uw * 16 + (ln & 15);
        const int cc  = kc * 32 + (ln >> 4) * 8;
        short8 hv; hi8s(Whh1 + j * 64 + cc, GF[g], hv);
        *(short8*)(Wlds + fid * WFR + ln * 8) = hv;
    }

    // ---- per-wave-role scalars + register weight matrix ----
    float ba[4], we[4];
    short8 wreg[8];      // L0: Whh0 frags; L1: Wih1 frags; decoder: Wchh frags
    const float* WmA = isL0 ? Whh0 : Wih1;
#pragma unroll
    for (int g = 0; g < 4; ++g) {
        const int j = g * 64 + uu;
        ba[g] = (isL0 ? (bih0[j] + bhh0[j]) : (bih1[j] + bhh1[j])) * GF[g];
        we[g] = Wih0[j] * GF[g];       // used by L0 only in encoder
#pragma unroll
        for (int kc = 0; kc < 2; ++kc)
            hi8s(WmA + j * 64 + kc * 32 + q * 8, GF[g], wreg[kc * 4 + g]);
    }

    float cs[8];         // c-state: L0 waves hold c0, L1 waves hold c1
#pragma unroll
    for (int i = 0; i < 8; ++i) cs[i] = 0.f;

    __syncthreads();   // Hhi zeroed + Wlds packed visible (full barrier, once)

// layer-0 step T: read h0 slot RP (0/1), write h0 slot WP
#define L0BODY(T, RP, WP) do {                                                        \
        _Pragma("unroll")                                                             \
        for (int mt = 0; mt < 2; ++mt) {                                              \
            const f32x4 xv = *(const f32x4*)(xbF + (T) * Sv + me + mt * 16);          \
            const short8 a0 = *(const short8*)(Hhi + (RP) * HBUF + roA + mt * 16 * HSTR);      \
            const short8 a1 = *(const short8*)(Hhi + (RP) * HBUF + roA + mt * 16 * HSTR + 32); \
            f32x4 pre[4];                                                             \
            _Pragma("unroll")                                                         \
            for (int g = 0; g < 4; ++g) pre[g] = (f32x4){ba[g], ba[g], ba[g], ba[g]}; \
            _Pragma("unroll")                                                         \
            for (int g = 0; g < 4; ++g) pre[g] = MFMA16(a0, wreg[g],     pre[g]);     \
            _Pragma("unroll")                                                         \
            for (int g = 0; g < 4; ++g) pre[g] = MFMA16(a1, wreg[4 + g], pre[g]);     \
            float hv[4];                                                              \
            _Pragma("unroll")                                                         \
            for (int r = 0; r < 4; ++r) {                                             \
                const float xw = xv[r];                                               \
                hv[r] = cell1(pre[0][r] + xw * we[0], pre[1][r] + xw * we[1],         \
                              pre[2][r] + xw * we[2], pre[3][r] + xw * we[3],         \
                              cs[mt * 4 + r]);                                        \
            }                                                                         \
            const unsigned p01 = pkbf16(hv[0], hv[1]);                                \
            const unsigned p23 = pkbf16(hv[2], hv[3]);                                \
            Hhi[(WP) * HBUF + wiA + (mt * 16 + 0) * HSTR] = (short)p01;               \
            Hhi[(WP) * HBUF + wiA + (mt * 16 + 1) * HSTR] = (short)(p01 >> 16);       \
            Hhi[(WP) * HBUF + wiA + (mt * 16 + 2) * HSTR] = (short)p23;               \
            Hhi[(WP) * HBUF + wiA + (mt * 16 + 3) * HSTR] = (short)(p23 >> 16);       \
        }                                                                             \
    } while (0)

// layer-1 step: read h0 slot RP0 (0/1), h1 slot RPH (2/3), write h1 slot WPH
#define L1BODY(RP0, RPH, WPH) do {                                                    \
        _Pragma("unroll")                                                             \
        for (int mt = 0; mt < 2; ++mt) {                                              \
            const short8 b0 = *(const short8*)(Hhi + (RP0) * HBUF + roA + mt * 16 * HSTR);      \
            const short8 b1 = *(const short8*)(Hhi + (RP0) * HBUF + roA + mt * 16 * HSTR + 32); \
            const short8 d0 = *(const short8*)(Hhi + (RPH) * HBUF + roA + mt * 16 * HSTR);      \
            const short8 d1 = *(const short8*)(Hhi + (RPH) * HBUF + roA + mt * 16 * HSTR + 32); \
            f32x4 pre[4];                                                             \
            _Pragma("unroll")                                                         \
            for (int g = 0; g < 4; ++g) pre[g] = (f32x4){ba[g], ba[g], ba[g], ba[g]}; \
            _Pragma("unroll")                                                         \
            for (int g = 0; g < 4; ++g) pre[g] = MFMA16(b0, wreg[g],     pre[g]);     \
            _Pragma("unroll")                                                         \
            for (int g = 0; g < 4; ++g) pre[g] = MFMA16(b1, wreg[4 + g], pre[g]);     \
            _Pragma("unroll")                                                         \
            for (int g = 0; g < 4; ++g) {                                             \
                const short8 wf = *(const short8*)(Wlds + wb + g * WFR);              \
                pre[g] = MFMA16(d0, wf, pre[g]);                                      \
            }                                                                         \
            _Pragma("unroll")                                                         \
            for (int g = 0; g < 4; ++g) {                                             \
                const short8 wf = *(const short8*)(Wlds + wb + (4 + g) * WFR);        \
                pre[g] = MFMA16(d1, wf, pre[g]);                                      \
            }                                                                         \
            float hv[4];                                                              \
            _Pragma("unroll")                                                         \
            for (int r = 0; r < 4; ++r)                                               \
                hv[r] = cell1(pre[0][r], pre[1][r], pre[2][r], pre[3][r],             \
                              cs[mt * 4 + r]);                                        \
            const unsigned p01 = pkbf16(hv[0], hv[1]);                                \
            const unsigned p23 = pkbf16(hv[2], hv[3]);                                \
            Hhi[(WPH) * HBUF + wiA + (mt * 16 + 0) * HSTR] = (short)p01;              \
            Hhi[(WPH) * HBUF + wiA + (mt * 16 + 1) * HSTR] = (short)(p01 >> 16);      \
            Hhi[(WPH) * HBUF + wiA + (mt * 16 + 2) * HSTR] = (short)p23;              \
            Hhi[(WPH) * HBUF + wiA + (mt * 16 + 3) * HSTR] = (short)(p23 >> 16);      \
        }                                                                             \
    } while (0)

    // ---- encoder: 169 barrier intervals; interval k runs L0(k) || L1(k-1) ----
    // h0(t) -> slot t&1; h1(t) -> slot 2+(t&1). Slots 1,3 start zeroed (= t=-1).
    // Raw barriers: all cross-wave deps here are LDS (lgkm); WAR on slots is
    // covered because each wave's own ds_reads are <= its lgkmcnt(0) at the
    // same barrier the writer waits on.
    if (isL0) L0BODY(0, 1, 0);
    ENCBAR();
    for (int k = 1; k < 167; k += 2) {
        // odd interval k: L0(k): rd h0[0] wr h0[1]; L1(k-1): rd h0[0],h1[3] wr h1[2]
        if (isL0) L0BODY(k, 0, 1); else L1BODY(0, 3, 2);
        ENCBAR();
        // even interval k+1: L0: rd h0[1] wr h0[0]; L1(k): rd h0[1],h1[2] wr h1[3]
        if (isL0) L0BODY(k + 1, 1, 0); else L1BODY(1, 2, 3);
        ENCBAR();
    }
    if (isL0) L0BODY(167, 0, 1); else L1BODY(0, 3, 2);   // interval 167 (odd)
    ENCBAR();
    if (!isL0) L1BODY(1, 2, 3);                          // interval 168: L1(167) only
    __syncthreads();   // full barrier at encoder/decoder boundary
    // h1(167) now in slot 3; c1 state lives in L1 waves' cs[8]

    // ================= decoder (runs on L1 waves; projection on all) =================
#pragma unroll
    for (int g = 0; g < 4; ++g) {
        const int j = g * 64 + uu;
        ba[g] = (bcih[j] + bchh[j]) * GF[g];
        we[g] = Wcih[j] * GF[g];
#pragma unroll
        for (int kc = 0; kc < 2; ++kc)
            hi8s(Wchh + j * 64 + kc * 32 + q * 8, GF[g], wreg[kc * 4 + g]);
    }
    if (tid < Mv) ybufF[tid] = xbF[(Lv - 1) * Sv + tid];
    __syncthreads();   // ybufF visible (h1 slot 3 already visible)

    const float boutF = bout[0];
    float* outp = out + b * HZv * Sv + s0;

#define DECBODY(T, RPH, WPH) do {                                                     \
        if (!isL0) {                                                                  \
            _Pragma("unroll")                                                         \
            for (int mt = 0; mt < 2; ++mt) {                                          \
                const f32x4 yv = *(const f32x4*)(ybufF + me + mt * 16);               \
                const short8 a0 = *(const short8*)(Hhi + (RPH) * HBUF + roA + mt * 16 * HSTR);      \
                const short8 a1 = *(const short8*)(Hhi + (RPH) * HBUF + roA + mt * 16 * HSTR + 32); \
                f32x4 pre[4];                                                         \
                _Pragma("unroll")                                                     \
                for (int g = 0; g < 4; ++g) pre[g] = (f32x4){ba[g], ba[g], ba[g], ba[g]}; \
                _Pragma("unroll")                                                     \
                for (int g = 0; g < 4; ++g) pre[g] = MFMA16(a0, wreg[g],     pre[g]); \
                _Pragma("unroll")                                                     \
                for (int g = 0; g < 4; ++g) pre[g] = MFMA16(a1, wreg[4 + g], pre[g]); \
                float hv[4];                                                          \
                _Pragma("unroll")                                                     \
                for (int r = 0; r < 4; ++r) {                                         \
                    const float xw = yv[r];                                           \
                    hv[r] = cell1(pre[0][r] + xw * we[0], pre[1][r] + xw * we[1],     \
                                  pre[2][r] + xw * we[2], pre[3][r] + xw * we[3],     \
                                  cs[mt * 4 + r]);                                    \
                }                                                                     \
                const unsigned p01 = pkbf16(hv[0], hv[1]);                            \
                const unsigned p23 = pkbf16(hv[2], hv[3]);                            \
                Hhi[(WPH) * HBUF + wiA + (mt * 16 + 0) * HSTR] = (short)p01;          \
                Hhi[(WPH) * HBUF + wiA + (mt * 16 + 1) * HSTR] = (short)(p01 >> 16);  \
                Hhi[(WPH) * HBUF + wiA + (mt * 16 + 2) * HSTR] = (short)p23;          \
                Hhi[(WPH) * HBUF + wiA + (mt * 16 + 3) * HSTR] = (short)(p23 >> 16);  \
            }                                                                         \
        }                                                                             \
        __syncthreads();   /* h(new) visible for y projection */                      \
        {                  /* all 1024 threads: 16 lanes per m, 4 k each */           \
            const int m  = tid >> 4;                                                  \
            const int pp = tid & 15;                                                  \
            float s = 0.f;                                                            \
            _Pragma("unroll")                                                         \
            for (int k2 = 0; k2 < 4; ++k2)                                            \
                s += b2f(Hhi[(WPH) * HBUF + m * HSTR + pp * 4 + k2]) * woutF[pp * 4 + k2]; \
            s += __shfl_xor(s, 1, 64);                                                \
            s += __shfl_xor(s, 2, 64);                                                \
            s += __shfl_xor(s, 4, 64);                                                \
            s += __shfl_xor(s, 8, 64);                                                \
            if (pp == 0) {                                                            \
                const float y = s + boutF;                                            \
                outp[(T) * Sv + m] = y;                                               \
                ybufF[m] = y;                                                         \
            }                                                                         \
        }                                                                             \
        __syncthreads();   /* ybufF visible for next step */                          \
    } while (0)

    for (int t = 0; t < HZv; t += 2) {
        DECBODY(t,     3, 2);
        DECBODY(t + 1, 2, 3);
    }
#undef DECBODY
#undef L1BODY
#undef L0BODY
}

extern "C" void kernel_launch(void* const* d_in, const int* in_sizes, int n_in,
                              void* d_out, int out_size, void* d_ws, size_t ws_size,
                              hipStream_t stream)
{
    const float* x_seq = (const float*)d_in[0];
    const float* Wih0  = (const float*)d_in[1];
    const float* Whh0  = (const float*)d_in[2];
    const float* bih0  = (const float*)d_in[3];
    const float* bhh0  = (const float*)d_in[4];
    const float* Wih1  = (const float*)d_in[5];
    const float* Whh1  = (const float*)d_in[6];
    const float* bih1  = (const float*)d_in[7];
    const float* bhh1  = (const float*)d_in[8];
    const float* Wcih  = (const float*)d_in[9];
    const float* Wchh  = (const float*)d_in[10];
    const float* bcih  = (const float*)d_in[11];
    const float* bchh  = (const float*)d_in[12];
    const float* Wout  = (const float*)d_in[13];
    const float* bout  = (const float*)d_in[14];
    float* out = (float*)d_out;

    hipLaunchKernelGGL(sitewise_lstm, dim3(Bv * (Sv / Mv)), dim3(1024), 0, stream,
                       x_seq, Wih0, Whh0, bih0, bhh0, Wih1, Whh1, bih1, bhh1,
                       Wcih, Wchh, bcih, bchh, Wout, bout, out);
}